// Round 6
// baseline (163.302 us; speedup 1.0000x reference)
//
#include <hip/hip_runtime.h>
#include <math.h>

#define N_    32
#define C_    512
#define P_    1024
#define KG_   10
#define KV_   8
#define PBLK_ 64
#define NPB_  (P_ / PBLK_)   // 16
#define PS_   81             // logits-partial row stride (conflict-free)
#define AS_   72             // a_l row stride
#define XAS_  521            // sm_ax row stride (9*k mod 32 -> distinct banks)

// ---------------------------------------------------------------------------
// Main kernel: block = (n, 64-p chunk), 512 threads = 8 waves. Wave cg owns
// c in [cg*64,(cg+1)*64); lane <-> p. x[64c][1p] loaded ONCE into registers
// (xv[64]) and used for BOTH logits (phase 1) and partial ax (phase 3).
// w indices are wave-uniform -> scalar s_loads. Grid N*16 = 512 blocks,
// 2 blocks/CU (VGPR-capped), phase-1 memory overlaps phase-3 VALU across
// the two resident blocks.
// ---------------------------------------------------------------------------
__global__ __launch_bounds__(512, 4) void vlad_main(
    const float* __restrict__ x, const float* __restrict__ w,
    const float* __restrict__ bias,
    float* __restrict__ part_ax, float* __restrict__ asum_blk) {
  __shared__ float part[PBLK_ * PS_];   // 20736 B  logits partials
  __shared__ float a_l[KV_ * AS_];      //  2304 B  a[k][p]
  __shared__ float sm_ax[KV_ * XAS_];   // 16672 B  ax[k][c] block partial

  const int t    = threadIdx.x;
  const int lane = t & 63;                                   // <-> p
  const int cg   = __builtin_amdgcn_readfirstlane(t >> 6);   // 0..7
  const int n    = blockIdx.x >> 4;
  const int pb   = blockIdx.x & 15;
  const int p0   = pb * PBLK_;
  const int c0   = cg * 64;

  // ---- phase 1a: load x[64 c][p=lane] into registers (64 indep loads) ----
  const float* xp = x + ((size_t)n * C_ + c0) * P_ + p0 + lane;
  float xv[64];
#pragma unroll
  for (int i = 0; i < 64; ++i) xv[i] = xp[(size_t)i * P_];

  // ---- phase 1b: logits partials; w via scalar pipe ----
  float acc[KG_];
#pragma unroll
  for (int k = 0; k < KG_; ++k) acc[k] = 0.f;
#pragma unroll
  for (int i = 0; i < 64; ++i) {
#pragma unroll
    for (int k = 0; k < KG_; ++k) acc[k] += xv[i] * w[k * C_ + c0 + i];
  }
#pragma unroll
  for (int k = 0; k < KG_; ++k) part[lane * PS_ + cg * KG_ + k] = acc[k];
  __syncthreads();

  // ---- phase 2: wave 0 combines + softmax; writes a_l LDS + asum global ----
  if (t < 64) {
    float l[KG_];
    float m = -1e30f;
#pragma unroll
    for (int k = 0; k < KG_; ++k) {
      float s = bias[k];
#pragma unroll
      for (int g = 0; g < 8; ++g) s += part[t * PS_ + g * KG_ + k];
      l[k] = s;
      m = fmaxf(m, s);
    }
    float sum = 0.f;
#pragma unroll
    for (int k = 0; k < KG_; ++k) { l[k] = __expf(l[k] - m); sum += l[k]; }
    const float inv = 1.f / sum;
#pragma unroll
    for (int k = 0; k < KV_; ++k) {
      const float a = l[k] * inv;
      a_l[k * AS_ + t] = a;
      float s = a;                         // sum over 64 p (lanes)
      s += __shfl_xor(s, 1, 64);  s += __shfl_xor(s, 2, 64);
      s += __shfl_xor(s, 4, 64);  s += __shfl_xor(s, 8, 64);
      s += __shfl_xor(s, 16, 64); s += __shfl_xor(s, 32, 64);
      if (t == 0) asum_blk[(n * NPB_ + pb) * KV_ + k] = s;
    }
  }
  __syncthreads();

  // ---- phase 3: partial ax[c][k] = sum_p a[k][p] * x[c][p] from registers.
  // Per c: 8 products/lane -> split-butterfly (xor 1,2,4) -> plain (8,16,32);
  // lane l<8 ends holding total for k = ((l&1)<<2)|(l&2)|((l>>2)&1).
  float ak[KV_];
#pragma unroll
  for (int k = 0; k < KV_; ++k) ak[k] = a_l[k * AS_ + lane];

  const int kmap = ((lane & 1) << 2) | (lane & 2) | ((lane >> 2) & 1);

#pragma unroll 8
  for (int i = 0; i < 64; ++i) {
    float v[KV_];
#pragma unroll
    for (int k = 0; k < KV_; ++k) v[k] = ak[k] * xv[i];
    {  // xor1: 8 -> 4
      const bool hi = lane & 1;
#pragma unroll
      for (int j = 0; j < 4; ++j) {
        float send = hi ? v[j] : v[j + 4];
        float keep = hi ? v[j + 4] : v[j];
        v[j] = keep + __shfl_xor(send, 1, 64);
      }
    }
    {  // xor2: 4 -> 2
      const bool hi = lane & 2;
#pragma unroll
      for (int j = 0; j < 2; ++j) {
        float send = hi ? v[j] : v[j + 2];
        float keep = hi ? v[j + 2] : v[j];
        v[j] = keep + __shfl_xor(send, 2, 64);
      }
    }
    {  // xor4: 2 -> 1
      const bool hi = lane & 4;
      float send = hi ? v[0] : v[1];
      float keep = hi ? v[1] : v[0];
      v[0] = keep + __shfl_xor(send, 4, 64);
    }
    v[0] += __shfl_xor(v[0], 8, 64);
    v[0] += __shfl_xor(v[0], 16, 64);
    v[0] += __shfl_xor(v[0], 32, 64);
    if (lane < 8) sm_ax[kmap * XAS_ + c0 + i] = v[0];
  }
  __syncthreads();

  // ---- dump sm_ax -> global, coalesced: part_ax[(n,pb)][k][c] ----
  const size_t base = (size_t)(n * NPB_ + pb) * KV_ * C_;
#pragma unroll
  for (int r = 0; r < 8; ++r) {
    const int idx = r * 512 + t;
    const int k = idx >> 9;
    const int c = idx & 511;
    part_ax[base + idx] = sm_ax[k * XAS_ + c];
  }
}

// ---------------------------------------------------------------------------
// Fin: sum 16 pb-partials (L2-hot), asum, residual vs centers, L2 normalize,
// write. Grid N*8 = 256 blocks of 256 threads; thread handles 2 c (float2).
// ---------------------------------------------------------------------------
__global__ __launch_bounds__(256) void vlad_fin(
    const float* __restrict__ part_ax, const float* __restrict__ asum_blk,
    const float* __restrict__ centers, float* __restrict__ out) {
  __shared__ float sred[4];
  const int n = blockIdx.x >> 3;
  const int k = blockIdx.x & 7;
  const int t = threadIdx.x, lane = t & 63, wv = t >> 6;

  float asv = 0.f;
#pragma unroll
  for (int pb = 0; pb < NPB_; ++pb)                 // uniform -> s_loads
    asv += asum_blk[(n * NPB_ + pb) * KV_ + k];

  const int c = t * 2;
  float s0 = 0.f, s1 = 0.f;
#pragma unroll
  for (int pb = 0; pb < NPB_; ++pb) {
    const float2 v = *reinterpret_cast<const float2*>(
        &part_ax[((size_t)(n * NPB_ + pb) * KV_ + k) * C_ + c]);
    s0 += v.x; s1 += v.y;
  }
  const float2 ct = *reinterpret_cast<const float2*>(&centers[k * C_ + c]);
  const float r0 = s0 - asv * ct.x;
  const float r1 = s1 - asv * ct.y;

  float ss = r0 * r0 + r1 * r1;
#pragma unroll
  for (int d = 1; d < 64; d <<= 1) ss += __shfl_xor(ss, d, 64);
  if (lane == 0) sred[wv] = ss;
  __syncthreads();
  const float tot = (sred[0] + sred[1]) + (sred[2] + sred[3]);
  const float inv = 1.f / fmaxf(sqrtf(tot), 1e-12f);

  float2 o;
  o.x = r0 * inv;
  o.y = r1 * inv;
  *reinterpret_cast<float2*>(&out[(size_t)n * (KV_ * C_) + k * C_ + c]) = o;
}

extern "C" void kernel_launch(void* const* d_in, const int* in_sizes, int n_in,
                              void* d_out, int out_size, void* d_ws, size_t ws_size,
                              hipStream_t stream) {
  const float* x       = (const float*)d_in[0];
  const float* conv_w  = (const float*)d_in[1];
  const float* conv_b  = (const float*)d_in[2];
  const float* centers = (const float*)d_in[3];
  float* out = (float*)d_out;

  float* part_ax  = (float*)d_ws;                              // 8 MiB
  float* asum_blk = part_ax + (size_t)N_ * NPB_ * KV_ * C_;    // 16 KiB

  hipLaunchKernelGGL(vlad_main, dim3(N_ * NPB_), dim3(512), 0, stream,
                     x, conv_w, conv_b, part_ax, asum_blk);
  hipLaunchKernelGGL(vlad_fin,  dim3(N_ * KV_),  dim3(256), 0, stream,
                     part_ax, asum_blk, centers, out);
}

// Round 7
// 133.973 us; speedup vs baseline: 1.2189x; 1.2189x over previous
//
#include <hip/hip_runtime.h>
#include <math.h>

#define N_    32
#define C_    512
#define P_    1024
#define KG_   10
#define KV_   8
#define PBLK_ 128
#define NPB_  (P_ / PBLK_)   // 8
#define PS_   81             // part row stride (odd*? -> conflict-light)

// ---------------------------------------------------------------------------
// K1: logits + softmax. Block = (n, 128-p chunk), 512 threads = 8 waves.
// Wave cg reduces c in [cg*64,(cg+1)*64): w[k][c] wave-uniform -> scalar
// s_loads (never in the vector-load FIFO). Lane <-> 2 p's via float2 loads
// (512 B per wave-instr). Tail parallel across all 8 waves (16 p each).
// Grid: N*8 = 256 blocks -> 1 block/CU, 8 waves/CU.
// ---------------------------------------------------------------------------
__global__ __launch_bounds__(512) void vlad_logits(
    const float* __restrict__ x, const float* __restrict__ w,
    const float* __restrict__ bias, float* __restrict__ a_ws,
    float* __restrict__ asum_blk) {
  __shared__ float part[PBLK_ * PS_];   // 41472 B
  const int t  = threadIdx.x;
  const int lane = t & 63;
  const int cg = __builtin_amdgcn_readfirstlane(t >> 6);  // 0..7
  const int n  = blockIdx.x >> 3;
  const int pb = blockIdx.x & 7;
  const int p0 = pb * PBLK_;
  const int c0 = cg * 64;

  const float* xp = x + ((size_t)n * C_ + c0) * P_ + p0 + lane * 2;

  float accA[KG_], accB[KG_];
#pragma unroll
  for (int k = 0; k < KG_; ++k) { accA[k] = 0.f; accB[k] = 0.f; }

#pragma unroll 8
  for (int i = 0; i < 64; ++i) {
    const float2 xv = *reinterpret_cast<const float2*>(xp + (size_t)i * P_);
#pragma unroll
    for (int k = 0; k < KG_; ++k) {
      const float wk = w[k * C_ + c0 + i];   // uniform -> s_load
      accA[k] += xv.x * wk;
      accB[k] += xv.y * wk;
    }
  }

#pragma unroll
  for (int k = 0; k < KG_; ++k) {
    part[(lane * 2 + 0) * PS_ + cg * KG_ + k] = accA[k];
    part[(lane * 2 + 1) * PS_ + cg * KG_ + k] = accB[k];
  }
  __syncthreads();

  // tail: wave cg handles p rows [cg*16, cg*16+16), lanes 0..15 active
  if (lane < 16) {
    const int p = cg * 16 + lane;
    float l[KG_];
    float m = -1e30f;
#pragma unroll
    for (int k = 0; k < KG_; ++k) {
      float s = bias[k];
#pragma unroll
      for (int g = 0; g < 8; ++g) s += part[p * PS_ + g * KG_ + k];
      l[k] = s;
      m = fmaxf(m, s);
    }
    float sum = 0.f;
#pragma unroll
    for (int k = 0; k < KG_; ++k) { l[k] = __expf(l[k] - m); sum += l[k]; }
    const float inv = 1.f / sum;
#pragma unroll
    for (int k = 0; k < KV_; ++k) {
      const float a = l[k] * inv;
      a_ws[((size_t)n * KV_ + k) * P_ + p0 + p] = a;
      float s = a;                       // reduce over the 16 active lanes
      s += __shfl_xor(s, 1, 64);
      s += __shfl_xor(s, 2, 64);
      s += __shfl_xor(s, 4, 64);
      s += __shfl_xor(s, 8, 64);
      if (lane == 0)
        asum_blk[(size_t)((n * NPB_ + pb) * 8 + cg) * KV_ + k] = s;
    }
  }
}

// ---------------------------------------------------------------------------
// K2: ax[n][k][c] = sum_p a[n][k][p] * x[n][c][p]. Block = (n, 16-c slice)
// covering ALL p -> writes final ax. Wave owns 4 c's; lanes <-> p via float4.
// x second read is L3-hot; a is L2-hot. Grid: N*32 = 1024 blocks of 256.
// ---------------------------------------------------------------------------
__global__ __launch_bounds__(256) void vlad_ax(
    const float* __restrict__ x, const float* __restrict__ a_ws,
    float* __restrict__ ax_ws) {
  const int n    = blockIdx.x >> 5;
  const int cb   = blockIdx.x & 31;
  const int lane = threadIdx.x & 63;
  const int wv   = threadIdx.x >> 6;
  const int c0   = cb * 16 + wv * 4;

  const float* ap = a_ws + (size_t)n * KV_ * P_;
  const float* xp = x + (size_t)n * C_ * P_;

  float acc[4][8];
#pragma unroll
  for (int cc = 0; cc < 4; ++cc)
#pragma unroll
    for (int k = 0; k < 8; ++k) acc[cc][k] = 0.f;

#pragma unroll
  for (int i = 0; i < 4; ++i) {
    const int pb = i * 256 + lane * 4;
    float4 a4[8];
#pragma unroll
    for (int k = 0; k < 8; ++k)
      a4[k] = *reinterpret_cast<const float4*>(ap + (size_t)k * P_ + pb);
#pragma unroll
    for (int cc = 0; cc < 4; ++cc) {
      float4 x4 = *reinterpret_cast<const float4*>(xp + (size_t)(c0 + cc) * P_ + pb);
#pragma unroll
      for (int k = 0; k < 8; ++k)
        acc[cc][k] += x4.x * a4[k].x + x4.y * a4[k].y
                    + x4.z * a4[k].z + x4.w * a4[k].w;
    }
  }

  float v[32];
#pragma unroll
  for (int cc = 0; cc < 4; ++cc)
#pragma unroll
    for (int k = 0; k < 8; ++k) v[cc * 8 + k] = acc[cc][k];

  {  const bool hi = lane & 1;
#pragma unroll
    for (int j = 0; j < 16; ++j) {
      float send = hi ? v[j] : v[j + 16];
      float keep = hi ? v[j + 16] : v[j];
      v[j] = keep + __shfl_xor(send, 1, 64);
    } }
  {  const bool hi = lane & 2;
#pragma unroll
    for (int j = 0; j < 8; ++j) {
      float send = hi ? v[j] : v[j + 8];
      float keep = hi ? v[j + 8] : v[j];
      v[j] = keep + __shfl_xor(send, 2, 64);
    } }
  {  const bool hi = lane & 4;
#pragma unroll
    for (int j = 0; j < 4; ++j) {
      float send = hi ? v[j] : v[j + 4];
      float keep = hi ? v[j + 4] : v[j];
      v[j] = keep + __shfl_xor(send, 4, 64);
    } }
  {  const bool hi = lane & 8;
#pragma unroll
    for (int j = 0; j < 2; ++j) {
      float send = hi ? v[j] : v[j + 2];
      float keep = hi ? v[j + 2] : v[j];
      v[j] = keep + __shfl_xor(send, 8, 64);
    } }
  {  const bool hi = lane & 16;
    float send = hi ? v[0] : v[1];
    float keep = hi ? v[1] : v[0];
    v[0] = keep + __shfl_xor(send, 16, 64);
  }
  v[0] += __shfl_xor(v[0], 32, 64);

  if (lane < 32) {
    const int o = ((lane & 1) << 4) | ((lane & 2) << 2) | (lane & 4)
                | (((lane >> 3) & 1) << 1) | ((lane >> 4) & 1);
    const int cc = o >> 3;
    const int k  = o & 7;
    ax_ws[((size_t)n * KV_ + k) * C_ + (c0 + cc)] = v[0];
  }
}

// ---------------------------------------------------------------------------
// K3: asum (64 uniform partials), residual vs centers, L2 normalize, write.
// Grid: N*8 = 256 blocks of 256.
// ---------------------------------------------------------------------------
__global__ __launch_bounds__(256) void vlad_fin(
    const float* __restrict__ ax_ws, const float* __restrict__ asum_blk,
    const float* __restrict__ centers, float* __restrict__ out) {
  __shared__ float sred[4];
  const int n = blockIdx.x >> 3;
  const int k = blockIdx.x & 7;
  const int t = threadIdx.x, lane = t & 63, wv = t >> 6;

  float asv = 0.f;
#pragma unroll
  for (int j = 0; j < NPB_ * 8; ++j)                // uniform -> s_loads
    asv += asum_blk[(size_t)(n * NPB_ * 8 + j) * KV_ + k];

  const int c = t * 2;
  const float2 av = *reinterpret_cast<const float2*>(
      &ax_ws[((size_t)n * KV_ + k) * C_ + c]);
  const float2 ct = *reinterpret_cast<const float2*>(&centers[k * C_ + c]);
  const float r0 = av.x - asv * ct.x;
  const float r1 = av.y - asv * ct.y;

  float ss = r0 * r0 + r1 * r1;
#pragma unroll
  for (int d = 1; d < 64; d <<= 1) ss += __shfl_xor(ss, d, 64);
  if (lane == 0) sred[wv] = ss;
  __syncthreads();
  const float tot = (sred[0] + sred[1]) + (sred[2] + sred[3]);
  const float inv = 1.f / fmaxf(sqrtf(tot), 1e-12f);

  float2 o;
  o.x = r0 * inv;
  o.y = r1 * inv;
  *reinterpret_cast<float2*>(&out[(size_t)n * (KV_ * C_) + k * C_ + c]) = o;
}

extern "C" void kernel_launch(void* const* d_in, const int* in_sizes, int n_in,
                              void* d_out, int out_size, void* d_ws, size_t ws_size,
                              hipStream_t stream) {
  const float* x       = (const float*)d_in[0];
  const float* conv_w  = (const float*)d_in[1];
  const float* conv_b  = (const float*)d_in[2];
  const float* centers = (const float*)d_in[3];
  float* out = (float*)d_out;

  float* a_ws     = (float*)d_ws;                         // 1 MiB
  float* ax_ws    = a_ws + (size_t)N_ * KV_ * P_;         // 512 KiB
  float* asum_blk = ax_ws + (size_t)N_ * KV_ * C_;        // 64 KiB

  hipLaunchKernelGGL(vlad_logits, dim3(N_ * NPB_), dim3(512), 0, stream,
                     x, conv_w, conv_b, a_ws, asum_blk);
  hipLaunchKernelGGL(vlad_ax,     dim3(N_ * 32),  dim3(256), 0, stream,
                     x, a_ws, ax_ws);
  hipLaunchKernelGGL(vlad_fin,    dim3(N_ * KV_), dim3(256), 0, stream,
                     ax_ws, asum_blk, centers, out);
}

// Round 8
// 129.033 us; speedup vs baseline: 1.2656x; 1.0383x over previous
//
#include <hip/hip_runtime.h>
#include <math.h>

#define N_    32
#define C_    512
#define P_    1024
#define KG_   10
#define KV_   8
#define PBLK_ 64
#define NPB_  (P_ / PBLK_)   // 16
#define PS_   81             // part row stride (81 mod 32 = 17, conflict-free)

// ---------------------------------------------------------------------------
// K1: partial logits. Block = (n, pb, ch) reduces c in [ch*256,(ch+1)*256).
// 512 threads = 8 waves; wave cg owns 32 uniform c's (w -> scalar s_loads);
// lane <-> p (64 contiguous b32, 256 B per wave-instr). Grid N*32 = 1024
// blocks x 8 waves -> 4 blocks/CU = 32 waves/CU (vs R4's 16): doubles the
// number of independent load streams per CU.
// Output: plg[(n*16+pb)*2+ch][k][64p].
// ---------------------------------------------------------------------------
__global__ __launch_bounds__(512, 8) void vlad_logits_p(
    const float* __restrict__ x, const float* __restrict__ w,
    float* __restrict__ plg) {
  __shared__ float part[PBLK_ * PS_];   // 20736 B
  const int t    = threadIdx.x;
  const int lane = t & 63;
  const int cg   = __builtin_amdgcn_readfirstlane(t >> 6);  // 0..7
  const int bx   = blockIdx.x;
  const int n    = bx >> 5;
  const int pb   = (bx >> 1) & 15;
  const int ch   = bx & 1;
  const int p0   = pb * PBLK_;
  const int c0   = ch * 256 + cg * 32;

  const float* xp = x + ((size_t)n * C_ + c0) * P_ + p0 + lane;
  const float* wp = w + c0;

  float acc[KG_];
#pragma unroll
  for (int k = 0; k < KG_; ++k) acc[k] = 0.f;

#pragma unroll 8
  for (int i = 0; i < 32; ++i) {
    const float xv = xp[(size_t)i * P_];       // coalesced, independent
#pragma unroll
    for (int k = 0; k < KG_; ++k) acc[k] += xv * wp[k * C_ + i];  // s_load w
  }

#pragma unroll
  for (int k = 0; k < KG_; ++k) part[lane * PS_ + cg * KG_ + k] = acc[k];
  __syncthreads();

  if (t < 64) {
    const size_t row = (size_t)((n * NPB_ + pb) * 2 + ch) * KG_ * 64;
#pragma unroll
    for (int k = 0; k < KG_; ++k) {
      float s = 0.f;
#pragma unroll
      for (int g = 0; g < 8; ++g) s += part[t * PS_ + g * KG_ + k];
      plg[row + k * 64 + t] = s;               // coalesced 256 B stores
    }
  }
}

// ---------------------------------------------------------------------------
// K2: combine c-halves + bias, softmax over 10, write a + per-(n,64p) asum.
// 1 thread per p: grid N*4 = 128 blocks x 256 threads. 20 coalesced L2-hot
// loads + 10 exp per thread; latency-bound but tiny (~1-2 us).
// ---------------------------------------------------------------------------
__global__ __launch_bounds__(256) void vlad_softmax2(
    const float* __restrict__ plg, const float* __restrict__ bias,
    float* __restrict__ a_ws, float* __restrict__ asum_blk) {
  const int t  = threadIdx.x;
  const int n  = blockIdx.x >> 2;
  const int pq = blockIdx.x & 3;
  const int p  = pq * 256 + t;
  const int pb = p >> 6;          // global 64-p chunk: 0..15
  const int pl = p & 63;
  const int lane = t & 63;

  const size_t r0 = (size_t)((n * NPB_ + pb) * 2 + 0) * KG_ * 64;
  const size_t r1 = (size_t)((n * NPB_ + pb) * 2 + 1) * KG_ * 64;

  float l[KG_];
  float m = -1e30f;
#pragma unroll
  for (int k = 0; k < KG_; ++k) {
    l[k] = plg[r0 + k * 64 + pl] + plg[r1 + k * 64 + pl] + bias[k];
    m = fmaxf(m, l[k]);
  }
  float sum = 0.f;
#pragma unroll
  for (int k = 0; k < KG_; ++k) { l[k] = __expf(l[k] - m); sum += l[k]; }
  const float inv = 1.f / sum;
#pragma unroll
  for (int k = 0; k < KV_; ++k) {
    const float a = l[k] * inv;
    a_ws[((size_t)n * KV_ + k) * P_ + p] = a;    // coalesced
    float s = a;                                 // reduce over 64 lanes = 64 p
    s += __shfl_xor(s, 1, 64);  s += __shfl_xor(s, 2, 64);
    s += __shfl_xor(s, 4, 64);  s += __shfl_xor(s, 8, 64);
    s += __shfl_xor(s, 16, 64); s += __shfl_xor(s, 32, 64);
    if (lane == 0) asum_blk[(n * NPB_ + pb) * KV_ + k] = s;
  }
}

// ---------------------------------------------------------------------------
// K3: ax[n][k][c] = sum_p a[n][k][p] * x[n][c][p]. Block = (n, 16-c slice)
// covering ALL p -> writes final ax. Wave owns 4 c's; lanes <-> p via float4.
// Grid: N*32 = 1024 blocks of 256.  (unchanged from R4)
// ---------------------------------------------------------------------------
__global__ __launch_bounds__(256) void vlad_ax(
    const float* __restrict__ x, const float* __restrict__ a_ws,
    float* __restrict__ ax_ws) {
  const int n    = blockIdx.x >> 5;
  const int cb   = blockIdx.x & 31;
  const int lane = threadIdx.x & 63;
  const int wv   = threadIdx.x >> 6;
  const int c0   = cb * 16 + wv * 4;

  const float* ap = a_ws + (size_t)n * KV_ * P_;
  const float* xp = x + (size_t)n * C_ * P_;

  float acc[4][8];
#pragma unroll
  for (int cc = 0; cc < 4; ++cc)
#pragma unroll
    for (int k = 0; k < 8; ++k) acc[cc][k] = 0.f;

#pragma unroll
  for (int i = 0; i < 4; ++i) {
    const int pb = i * 256 + lane * 4;
    float4 a4[8];
#pragma unroll
    for (int k = 0; k < 8; ++k)
      a4[k] = *reinterpret_cast<const float4*>(ap + (size_t)k * P_ + pb);
#pragma unroll
    for (int cc = 0; cc < 4; ++cc) {
      float4 x4 = *reinterpret_cast<const float4*>(xp + (size_t)(c0 + cc) * P_ + pb);
#pragma unroll
      for (int k = 0; k < 8; ++k)
        acc[cc][k] += x4.x * a4[k].x + x4.y * a4[k].y
                    + x4.z * a4[k].z + x4.w * a4[k].w;
    }
  }

  float v[32];
#pragma unroll
  for (int cc = 0; cc < 4; ++cc)
#pragma unroll
    for (int k = 0; k < 8; ++k) v[cc * 8 + k] = acc[cc][k];

  {  const bool hi = lane & 1;
#pragma unroll
    for (int j = 0; j < 16; ++j) {
      float send = hi ? v[j] : v[j + 16];
      float keep = hi ? v[j + 16] : v[j];
      v[j] = keep + __shfl_xor(send, 1, 64);
    } }
  {  const bool hi = lane & 2;
#pragma unroll
    for (int j = 0; j < 8; ++j) {
      float send = hi ? v[j] : v[j + 8];
      float keep = hi ? v[j + 8] : v[j];
      v[j] = keep + __shfl_xor(send, 2, 64);
    } }
  {  const bool hi = lane & 4;
#pragma unroll
    for (int j = 0; j < 4; ++j) {
      float send = hi ? v[j] : v[j + 4];
      float keep = hi ? v[j + 4] : v[j];
      v[j] = keep + __shfl_xor(send, 4, 64);
    } }
  {  const bool hi = lane & 8;
#pragma unroll
    for (int j = 0; j < 2; ++j) {
      float send = hi ? v[j] : v[j + 2];
      float keep = hi ? v[j + 2] : v[j];
      v[j] = keep + __shfl_xor(send, 8, 64);
    } }
  {  const bool hi = lane & 16;
    float send = hi ? v[0] : v[1];
    float keep = hi ? v[1] : v[0];
    v[0] = keep + __shfl_xor(send, 16, 64);
  }
  v[0] += __shfl_xor(v[0], 32, 64);

  if (lane < 32) {
    const int o = ((lane & 1) << 4) | ((lane & 2) << 2) | (lane & 4)
                | (((lane >> 3) & 1) << 1) | ((lane >> 4) & 1);
    const int cc = o >> 3;
    const int k  = o & 7;
    ax_ws[((size_t)n * KV_ + k) * C_ + (c0 + cc)] = v[0];
  }
}

// ---------------------------------------------------------------------------
// K4: asum (16 uniform partials), residual vs centers, L2 normalize, write.
// Grid: N*8 = 256 blocks of 256.  (unchanged from R4)
// ---------------------------------------------------------------------------
__global__ __launch_bounds__(256) void vlad_fin(
    const float* __restrict__ ax_ws, const float* __restrict__ asum_blk,
    const float* __restrict__ centers, float* __restrict__ out) {
  __shared__ float sred[4];
  const int n = blockIdx.x >> 3;
  const int k = blockIdx.x & 7;
  const int t = threadIdx.x, lane = t & 63, wv = t >> 6;

  float asv = 0.f;
#pragma unroll
  for (int pb = 0; pb < NPB_; ++pb)                 // uniform -> s_loads
    asv += asum_blk[(n * NPB_ + pb) * KV_ + k];

  const int c = t * 2;
  const float2 av = *reinterpret_cast<const float2*>(
      &ax_ws[((size_t)n * KV_ + k) * C_ + c]);
  const float2 ct = *reinterpret_cast<const float2*>(&centers[k * C_ + c]);
  const float r0 = av.x - asv * ct.x;
  const float r1 = av.y - asv * ct.y;

  float ss = r0 * r0 + r1 * r1;
#pragma unroll
  for (int d = 1; d < 64; d <<= 1) ss += __shfl_xor(ss, d, 64);
  if (lane == 0) sred[wv] = ss;
  __syncthreads();
  const float tot = (sred[0] + sred[1]) + (sred[2] + sred[3]);
  const float inv = 1.f / fmaxf(sqrtf(tot), 1e-12f);

  float2 o;
  o.x = r0 * inv;
  o.y = r1 * inv;
  *reinterpret_cast<float2*>(&out[(size_t)n * (KV_ * C_) + k * C_ + c]) = o;
}

extern "C" void kernel_launch(void* const* d_in, const int* in_sizes, int n_in,
                              void* d_out, int out_size, void* d_ws, size_t ws_size,
                              hipStream_t stream) {
  const float* x       = (const float*)d_in[0];
  const float* conv_w  = (const float*)d_in[1];
  const float* conv_b  = (const float*)d_in[2];
  const float* centers = (const float*)d_in[3];
  float* out = (float*)d_out;

  float* plg      = (float*)d_ws;                             // 2.62 MB
  float* a_ws     = plg + (size_t)N_ * NPB_ * 2 * KG_ * 64;   // 1 MiB
  float* ax_ws    = a_ws + (size_t)N_ * KV_ * P_;             // 512 KiB
  float* asum_blk = ax_ws + (size_t)N_ * KV_ * C_;            // 16 KiB

  hipLaunchKernelGGL(vlad_logits_p, dim3(N_ * 32), dim3(512), 0, stream,
                     x, conv_w, plg);
  hipLaunchKernelGGL(vlad_softmax2, dim3(N_ * 4),  dim3(256), 0, stream,
                     plg, conv_b, a_ws, asum_blk);
  hipLaunchKernelGGL(vlad_ax,       dim3(N_ * 32), dim3(256), 0, stream,
                     x, a_ws, ax_ws);
  hipLaunchKernelGGL(vlad_fin,      dim3(N_ * KV_), dim3(256), 0, stream,
                     ax_ws, asum_blk, centers, out);
}

// Round 9
// 128.007 us; speedup vs baseline: 1.2757x; 1.0080x over previous
//
#include <hip/hip_runtime.h>
#include <math.h>

#define N_    32
#define C_    512
#define P_    1024
#define KG_   10
#define KV_   8
#define PBLK_ 64
#define NPB_  (P_ / PBLK_)   // 16
#define PS_   161            // part row stride (161 mod 32 = 1 -> conflict-free)

// ---------------------------------------------------------------------------
// K1: logits + softmax. Block = (n, 64-p chunk), 1024 threads = 16 waves.
// Wave cg reduces c in [cg*32,(cg+1)*32): w[k][c] wave-uniform -> scalar
// s_loads. Lane <-> p (64 contiguous b32 = 256 B per wave-instr). Grid
// N*16 = 512 blocks -> 2 blocks/CU = 32 waves/CU (2x R4's resident waves,
// same dispatch count, no partial-logits round-trip).
// ---------------------------------------------------------------------------
__global__ __launch_bounds__(1024, 8) void vlad_logits(
    const float* __restrict__ x, const float* __restrict__ w,
    const float* __restrict__ bias, float* __restrict__ a_ws,
    float* __restrict__ asum_blk) {
  __shared__ float part[PBLK_ * PS_];   // 41216 B
  const int t    = threadIdx.x;
  const int lane = t & 63;
  const int cg   = __builtin_amdgcn_readfirstlane(t >> 6);  // 0..15
  const int n    = blockIdx.x >> 4;
  const int pb   = blockIdx.x & 15;
  const int p0   = pb * PBLK_;
  const int c0   = cg * 32;

  const float* xp = x + ((size_t)n * C_ + c0) * P_ + p0 + lane;
  const float* wp = w + c0;

  float acc[KG_];
#pragma unroll
  for (int k = 0; k < KG_; ++k) acc[k] = 0.f;

#pragma unroll 8
  for (int i = 0; i < 32; ++i) {
    const float xv = xp[(size_t)i * P_];       // coalesced, independent
#pragma unroll
    for (int k = 0; k < KG_; ++k) acc[k] += xv * wp[k * C_ + i];  // s_load w
  }

#pragma unroll
  for (int k = 0; k < KG_; ++k) part[lane * PS_ + cg * KG_ + k] = acc[k];
  __syncthreads();

  // tail: wave 0, lane t <-> p; combine 16 c-group partials + softmax
  if (t < 64) {
    float l[KG_];
    float m = -1e30f;
#pragma unroll
    for (int k = 0; k < KG_; ++k) {
      float s = bias[k];
#pragma unroll
      for (int g = 0; g < 16; ++g) s += part[t * PS_ + g * KG_ + k];
      l[k] = s;
      m = fmaxf(m, s);
    }
    float sum = 0.f;
#pragma unroll
    for (int k = 0; k < KG_; ++k) { l[k] = __expf(l[k] - m); sum += l[k]; }
    const float inv = 1.f / sum;
#pragma unroll
    for (int k = 0; k < KV_; ++k) {
      const float a = l[k] * inv;
      a_ws[((size_t)n * KV_ + k) * P_ + p0 + t] = a;   // coalesced 256 B
      float s = a;                                     // reduce over 64 p
      s += __shfl_xor(s, 1, 64);  s += __shfl_xor(s, 2, 64);
      s += __shfl_xor(s, 4, 64);  s += __shfl_xor(s, 8, 64);
      s += __shfl_xor(s, 16, 64); s += __shfl_xor(s, 32, 64);
      if (t == 0) asum_blk[(n * NPB_ + pb) * KV_ + k] = s;
    }
  }
}

// ---------------------------------------------------------------------------
// K2: ax[n][k][c] = sum_p a[n][k][p] * x[n][c][p]. Block = (n, 16-c slice)
// covering ALL p -> writes final ax. Wave owns 4 c's; lanes <-> p via float4.
// Grid: N*32 = 1024 blocks of 256.  (unchanged from R4)
// ---------------------------------------------------------------------------
__global__ __launch_bounds__(256) void vlad_ax(
    const float* __restrict__ x, const float* __restrict__ a_ws,
    float* __restrict__ ax_ws) {
  const int n    = blockIdx.x >> 5;
  const int cb   = blockIdx.x & 31;
  const int lane = threadIdx.x & 63;
  const int wv   = threadIdx.x >> 6;
  const int c0   = cb * 16 + wv * 4;

  const float* ap = a_ws + (size_t)n * KV_ * P_;
  const float* xp = x + (size_t)n * C_ * P_;

  float acc[4][8];
#pragma unroll
  for (int cc = 0; cc < 4; ++cc)
#pragma unroll
    for (int k = 0; k < 8; ++k) acc[cc][k] = 0.f;

#pragma unroll
  for (int i = 0; i < 4; ++i) {
    const int pb = i * 256 + lane * 4;
    float4 a4[8];
#pragma unroll
    for (int k = 0; k < 8; ++k)
      a4[k] = *reinterpret_cast<const float4*>(ap + (size_t)k * P_ + pb);
#pragma unroll
    for (int cc = 0; cc < 4; ++cc) {
      float4 x4 = *reinterpret_cast<const float4*>(xp + (size_t)(c0 + cc) * P_ + pb);
#pragma unroll
      for (int k = 0; k < 8; ++k)
        acc[cc][k] += x4.x * a4[k].x + x4.y * a4[k].y
                    + x4.z * a4[k].z + x4.w * a4[k].w;
    }
  }

  float v[32];
#pragma unroll
  for (int cc = 0; cc < 4; ++cc)
#pragma unroll
    for (int k = 0; k < 8; ++k) v[cc * 8 + k] = acc[cc][k];

  {  const bool hi = lane & 1;
#pragma unroll
    for (int j = 0; j < 16; ++j) {
      float send = hi ? v[j] : v[j + 16];
      float keep = hi ? v[j + 16] : v[j];
      v[j] = keep + __shfl_xor(send, 1, 64);
    } }
  {  const bool hi = lane & 2;
#pragma unroll
    for (int j = 0; j < 8; ++j) {
      float send = hi ? v[j] : v[j + 8];
      float keep = hi ? v[j + 8] : v[j];
      v[j] = keep + __shfl_xor(send, 2, 64);
    } }
  {  const bool hi = lane & 4;
#pragma unroll
    for (int j = 0; j < 4; ++j) {
      float send = hi ? v[j] : v[j + 4];
      float keep = hi ? v[j + 4] : v[j];
      v[j] = keep + __shfl_xor(send, 4, 64);
    } }
  {  const bool hi = lane & 8;
#pragma unroll
    for (int j = 0; j < 2; ++j) {
      float send = hi ? v[j] : v[j + 2];
      float keep = hi ? v[j + 2] : v[j];
      v[j] = keep + __shfl_xor(send, 8, 64);
    } }
  {  const bool hi = lane & 16;
    float send = hi ? v[0] : v[1];
    float keep = hi ? v[1] : v[0];
    v[0] = keep + __shfl_xor(send, 16, 64);
  }
  v[0] += __shfl_xor(v[0], 32, 64);

  if (lane < 32) {
    const int o = ((lane & 1) << 4) | ((lane & 2) << 2) | (lane & 4)
                | (((lane >> 3) & 1) << 1) | ((lane >> 4) & 1);
    const int cc = o >> 3;
    const int k  = o & 7;
    ax_ws[((size_t)n * KV_ + k) * C_ + (c0 + cc)] = v[0];
  }
}

// ---------------------------------------------------------------------------
// K3: asum (16 uniform partials), residual vs centers, L2 normalize, write.
// Grid: N*8 = 256 blocks of 256.  (unchanged from R4)
// ---------------------------------------------------------------------------
__global__ __launch_bounds__(256) void vlad_fin(
    const float* __restrict__ ax_ws, const float* __restrict__ asum_blk,
    const float* __restrict__ centers, float* __restrict__ out) {
  __shared__ float sred[4];
  const int n = blockIdx.x >> 3;
  const int k = blockIdx.x & 7;
  const int t = threadIdx.x, lane = t & 63, wv = t >> 6;

  float asv = 0.f;
#pragma unroll
  for (int pb = 0; pb < NPB_; ++pb)                 // uniform -> s_loads
    asv += asum_blk[(n * NPB_ + pb) * KV_ + k];

  const int c = t * 2;
  const float2 av = *reinterpret_cast<const float2*>(
      &ax_ws[((size_t)n * KV_ + k) * C_ + c]);
  const float2 ct = *reinterpret_cast<const float2*>(&centers[k * C_ + c]);
  const float r0 = av.x - asv * ct.x;
  const float r1 = av.y - asv * ct.y;

  float ss = r0 * r0 + r1 * r1;
#pragma unroll
  for (int d = 1; d < 64; d <<= 1) ss += __shfl_xor(ss, d, 64);
  if (lane == 0) sred[wv] = ss;
  __syncthreads();
  const float tot = (sred[0] + sred[1]) + (sred[2] + sred[3]);
  const float inv = 1.f / fmaxf(sqrtf(tot), 1e-12f);

  float2 o;
  o.x = r0 * inv;
  o.y = r1 * inv;
  *reinterpret_cast<float2*>(&out[(size_t)n * (KV_ * C_) + k * C_ + c]) = o;
}

extern "C" void kernel_launch(void* const* d_in, const int* in_sizes, int n_in,
                              void* d_out, int out_size, void* d_ws, size_t ws_size,
                              hipStream_t stream) {
  const float* x       = (const float*)d_in[0];
  const float* conv_w  = (const float*)d_in[1];
  const float* conv_b  = (const float*)d_in[2];
  const float* centers = (const float*)d_in[3];
  float* out = (float*)d_out;

  float* a_ws     = (float*)d_ws;                         // 1 MiB
  float* ax_ws    = a_ws + (size_t)N_ * KV_ * P_;         // 512 KiB
  float* asum_blk = ax_ws + (size_t)N_ * KV_ * C_;        // 16 KiB

  hipLaunchKernelGGL(vlad_logits, dim3(N_ * NPB_), dim3(1024), 0, stream,
                     x, conv_w, conv_b, a_ws, asum_blk);
  hipLaunchKernelGGL(vlad_ax,     dim3(N_ * 32),  dim3(256), 0, stream,
                     x, a_ws, ax_ws);
  hipLaunchKernelGGL(vlad_fin,    dim3(N_ * KV_), dim3(256), 0, stream,
                     ax_ws, asum_blk, centers, out);
}